// Round 6
// baseline (529.702 us; speedup 1.0000x reference)
//
#include <hip/hip_runtime.h>
#include <hip/hip_bf16.h>
#include <math.h>

// Problem constants
#define BB 4
#define NN 2048
#define DM 1024
#define NH 16
#define DH 64

typedef short short8 __attribute__((ext_vector_type(8)));
typedef float f32x4 __attribute__((ext_vector_type(4)));

static __device__ __forceinline__ unsigned short f2bf(float x) {
  unsigned u = __builtin_bit_cast(unsigned, x);
  u += 0x7fffu + ((u >> 16) & 1u);            // RNE
  return (unsigned short)(u >> 16);
}
static __device__ __forceinline__ float bf2f(short s) {
  return __builtin_bit_cast(float, ((unsigned)(unsigned short)s) << 16);
}

typedef __attribute__((address_space(1))) const void gv_t;
typedef __attribute__((address_space(3))) void lv_t;
static __device__ __forceinline__ void gload16(const void* gsrc, void* ldst) {
  __builtin_amdgcn_global_load_lds((gv_t*)gsrc, (lv_t*)ldst, 16, 0, 0);
}

// ---------------------------------------------------------------------------
// pack f32 -> bf16, 8 elems/thread
// ---------------------------------------------------------------------------
__global__ __launch_bounds__(256) void pack_bf16(const float* __restrict__ in,
                                                 unsigned short* __restrict__ out,
                                                 int n8) {
  const int i = blockIdx.x * 256 + threadIdx.x;
  if (i >= n8) return;
  const float4* p = (const float4*)in + 2 * (size_t)i;
  const float4 x = p[0], y = p[1];
  unsigned short tmp[8] = {f2bf(x.x), f2bf(x.y), f2bf(x.z), f2bf(x.w),
                           f2bf(y.x), f2bf(y.y), f2bf(y.z), f2bf(y.w)};
  *(short8*)(out + 8 * (size_t)i) = *(const short8*)tmp;
}

// ---------------------------------------------------------------------------
// bf16 MFMA GEMM: C[M,N] f32 = A[M,K] * B[N,K]^T (both bf16 row-major).
// 128x128 tile, BK=32, 4 waves (2x2), 4x4 frags of 16x16x32 per wave.
// ---------------------------------------------------------------------------
__global__ __launch_bounds__(256) void gemm_bf16(const unsigned short* __restrict__ A,
                                                 const unsigned short* __restrict__ Bw,
                                                 float* __restrict__ C,
                                                 int M, int N, int K) {
  __shared__ unsigned short As[128 * 32];
  __shared__ unsigned short Bs[128 * 32];
  const int t = threadIdx.x;
  const int row0 = blockIdx.y * 128, col0 = blockIdx.x * 128;
  const int lane = t & 63, w = t >> 6;
  const int wr = (w >> 1) * 64, wc = (w & 1) * 64;
  const int g = lane >> 4, c = lane & 15;

  f32x4 acc[4][4];
  #pragma unroll
  for (int i = 0; i < 4; ++i)
    #pragma unroll
    for (int j = 0; j < 4; ++j) acc[i][j] = (f32x4){0.f, 0.f, 0.f, 0.f};

  const unsigned short* Asrc = A + (size_t)(row0 + (t >> 2)) * K + (t & 3) * 8;
  const unsigned short* Bsrc = Bw + (size_t)(col0 + (t >> 2)) * K + (t & 3) * 8;
  unsigned short* dA0 = &As[t * 8];
  unsigned short* dA1 = &As[2048 + t * 8];
  unsigned short* dB0 = &Bs[t * 8];
  unsigned short* dB1 = &Bs[2048 + t * 8];

  for (int kt = 0; kt < K; kt += 32) {
    __syncthreads();
    gload16(Asrc + kt, dA0);
    gload16(Asrc + (size_t)64 * K + kt, dA1);
    gload16(Bsrc + kt, dB0);
    gload16(Bsrc + (size_t)64 * K + kt, dB1);
    __syncthreads();
    short8 a[4], bf[4];
    #pragma unroll
    for (int i = 0; i < 4; ++i)
      a[i] = *(const short8*)&As[(wr + i * 16 + c) * 32 + g * 8];
    #pragma unroll
    for (int j = 0; j < 4; ++j)
      bf[j] = *(const short8*)&Bs[(wc + j * 16 + c) * 32 + g * 8];
    #pragma unroll
    for (int i = 0; i < 4; ++i)
      #pragma unroll
      for (int j = 0; j < 4; ++j)
        acc[i][j] = __builtin_amdgcn_mfma_f32_16x16x32_bf16(a[i], bf[j], acc[i][j], 0, 0, 0);
  }
  #pragma unroll
  for (int i = 0; i < 4; ++i) {
    #pragma unroll
    for (int r = 0; r < 4; ++r) {
      float* cp = C + (size_t)(row0 + wr + i * 16 + 4 * g + r) * N + col0 + wc + c;
      #pragma unroll
      for (int j = 0; j < 4; ++j) cp[j * 16] = acc[i][j][r];
    }
  }
}

// ---------------------------------------------------------------------------
// LayerNorm + bf16 pack: row of 1024 f32 (stride ldy) -> (b,h,n,d) bf16
// ---------------------------------------------------------------------------
__global__ __launch_bounds__(256) void ln_pack(const float* __restrict__ Y, int ldy,
                                               const float* __restrict__ g,
                                               const float* __restrict__ bb,
                                               unsigned short* __restrict__ out) {
  const int t = threadIdx.x;
  const int bidx = blockIdx.x >> 11;
  const int n = blockIdx.x & 2047;
  const float* y = Y + (size_t)blockIdx.x * ldy;
  float4 v = ((const float4*)y)[t];
  __shared__ float red[4];
  float s = v.x + v.y + v.z + v.w;
  #pragma unroll
  for (int off = 1; off < 64; off <<= 1) s += __shfl_xor(s, off, 64);
  if ((t & 63) == 0) red[t >> 6] = s;
  __syncthreads();
  const float mean = (red[0] + red[1] + red[2] + red[3]) * (1.f / 1024.f);
  const float dx = v.x - mean, dy = v.y - mean, dz = v.z - mean, dw = v.w - mean;
  float sq = dx * dx + dy * dy + dz * dz + dw * dw;
  #pragma unroll
  for (int off = 1; off < 64; off <<= 1) sq += __shfl_xor(sq, off, 64);
  __syncthreads();
  if ((t & 63) == 0) red[t >> 6] = sq;
  __syncthreads();
  const float inv = rsqrtf((red[0] + red[1] + red[2] + red[3]) * (1.f / 1024.f) + 1e-5f);
  const float4 gv = ((const float4*)g)[t];
  const float4 bv = ((const float4*)bb)[t];
  ushort4 w4;
  w4.x = f2bf(dx * inv * gv.x + bv.x);
  w4.y = f2bf(dy * inv * gv.y + bv.y);
  w4.z = f2bf(dz * inv * gv.z + bv.z);
  w4.w = f2bf(dw * inv * gv.w + bv.w);
  unsigned short* dst = out + (((size_t)bidx * NH + (t >> 4)) * NN + n) * DH + (t & 15) * 4;
  *(ushort4*)dst = w4;
}

// ---------------------------------------------------------------------------
// V pack + transpose: (b,n,f) f32 -> Vt (b,h,d,m) bf16
// ---------------------------------------------------------------------------
__global__ __launch_bounds__(256) void vpack(const float* __restrict__ V,
                                             unsigned short* __restrict__ Vt) {
  const int tid = blockIdx.x * 256 + threadIdx.x;
  const int d = tid & 63;
  const int rest = tid >> 6;
  const int m0 = (rest & 255) * 8;
  const int h = (rest >> 8) & 15;
  const int b = rest >> 12;
  const float* src = V + ((size_t)b * NN + m0) * DM + h * DH + d;
  unsigned short tmp[8];
  #pragma unroll
  for (int i = 0; i < 8; ++i) tmp[i] = f2bf(src[(size_t)i * DM]);
  unsigned short* dst = Vt + (((size_t)b * NH + h) * DH + d) * NN + m0;
  *(short8*)dst = *(const short8*)tmp;
}

// ---------------------------------------------------------------------------
// F_mask part1: per 64-row tile local prefix + tile sums.
// v2: 1 column/thread (grid 8x32x4 -> 2x threads) + 4-way partial accumulators
// to break the serial FMA chain.
// ---------------------------------------------------------------------------
__global__ __launch_bounds__(256) void fmask_part1(const unsigned short* __restrict__ Qh,
                                                   const unsigned short* __restrict__ Kh,
                                                   float* __restrict__ Fm,
                                                   float* __restrict__ BS) {
  const int b = blockIdx.z, tl = blockIdx.y;
  const int m = blockIdx.x * 256 + threadIdx.x;
  const int n0 = tl * 64;
  float kr[64];
  {
    const short8* kp = (const short8*)(Kh + ((size_t)b * NH * NN + m) * DH);
    #pragma unroll
    for (int i = 0; i < 8; ++i) {
      short8 kv = kp[i];
      #pragma unroll
      for (int j = 0; j < 8; ++j) kr[i * 8 + j] = bf2f(kv[j]);
    }
  }
  const float4* kv4 = (const float4*)kr;
  __shared__ float Qs[64][68];
  {
    const int row = threadIdx.x >> 2;
    const int c0 = (threadIdx.x & 3) * 16;
    const short8* qp = (const short8*)(Qh + ((size_t)b * NH * NN + n0 + row) * DH + c0);
    short8 qa = qp[0], qb2 = qp[1];
    #pragma unroll
    for (int j = 0; j < 8; ++j) {
      Qs[row][c0 + j] = bf2f(qa[j]);
      Qs[row][c0 + 8 + j] = bf2f(qb2[j]);
    }
  }
  __syncthreads();
  float run = 0.f;
  float* Fp = Fm + (size_t)b * NN * NN + m;
  for (int nn = 0; nn < 64; ++nn) {
    const int n = n0 + nn;
    Fp[(size_t)n * NN] = run;
    float d[4] = {0.f, 0.f, 0.f, 0.f};
    #pragma unroll
    for (int i = 0; i < 16; ++i) {
      const float4 qv = *(const float4*)&Qs[nn][i * 4];
      const float4 kv = kv4[i];
      d[i & 3] = fmaf(qv.x, kv.x, d[i & 3]);
      d[i & 3] = fmaf(qv.y, kv.y, d[i & 3]);
      d[i & 3] = fmaf(qv.z, kv.z, d[i & 3]);
      d[i & 3] = fmaf(qv.w, kv.w, d[i & 3]);
    }
    const float dot = (d[0] + d[1]) + (d[2] + d[3]);
    if (m >= 1 && m < n) run += fmaxf(dot * 0.125f, 0.f);
  }
  BS[((size_t)b * 32 + tl) * NN + m] = run;
}

// ---------------------------------------------------------------------------
// F_mask part2: add cross-tile prefix. grid (mc=8, t-1=31, b=4).
// ---------------------------------------------------------------------------
__global__ __launch_bounds__(256) void fmask_part2(const float* __restrict__ BS,
                                                   float* __restrict__ Fm) {
  const int b = blockIdx.z;
  const int tlt = blockIdx.y + 1;  // 1..31
  const int m = blockIdx.x * 256 + threadIdx.x;
  float pre = 0.f;
  const float* bs = BS + (size_t)b * 32 * NN + m;
  for (int t2 = 0; t2 < tlt; ++t2) pre += bs[(size_t)t2 * NN];
  float* Fp = Fm + ((size_t)b * NN + tlt * 64) * NN + m;
  #pragma unroll 4
  for (int nn = 0; nn < 64; ++nn) Fp[(size_t)nn * NN] += pre;
}

// ---------------------------------------------------------------------------
// MFMA flash attention v3: 4 waves / 64 q-rows, 64-m tiles, double-buffered
// 2-phase pipeline, causal pair balancing {bx, 31-bx}.
// New this round:
//  - XCD-aware 1D grid swizzle (1024 blocks, cpx=128): each XCD gets one b,
//    8 bx values, all 16 heads -> F rows reused 16x from its L2.
//  - Mask-free main loop (mask only needed on last tile: m0+63 <= q0w is
//    wave-uniform for mt < nt-1), masked tail tile peeled.
//  - Exact defer-max: skip O-rescale & max-update when __all(tmax <= mrun).
// Lane math identical to HW-verified rounds 2-5.
// ---------------------------------------------------------------------------
__global__ __launch_bounds__(256) void attn_mfma(const unsigned short* __restrict__ Qh,
                                                 const unsigned short* __restrict__ Kh,
                                                 const unsigned short* __restrict__ Vt,
                                                 const float* __restrict__ F,
                                                 unsigned short* __restrict__ Oh) {
  const int t = threadIdx.x, lane = t & 63, w = t >> 6;
  const int g = lane >> 4, c = lane & 15;
  // XCD swizzle: 1024 blocks = 8 XCDs x 128; h fastest so one XCD's chunk
  // covers all 16 heads for the same (b, bx-range) -> F L2 reuse.
  const int id = blockIdx.x;
  const int idp = (id & 7) * 128 + (id >> 3);
  const int h  = idp & 15;
  const int bx = (idp >> 4) & 15;
  const int b  = idp >> 8;
  const size_t bh = (size_t)b * NH + h;

  __shared__ union {
    struct { unsigned short Kf[2][8][64][8]; unsigned short Vf[2][8][64][8]; } tl;
    float Ot[4][16][68];
  } sm;

  const int perm = 8 * (c >> 2) + (c & 3);
  const int kr1 = 32 * (w >> 2) + perm + 4 * ((w >> 1) & 1);   // w<4 -> s=0
  const unsigned short* srcK1 = Kh + (bh * NN + kr1) * DH + g * 8 + 32 * (w & 1);
  const unsigned short* srcK2 = srcK1 + (size_t)32 * DH;       // frag w+4 (s=1)
  const unsigned short* srcV1 = Vt + (bh * DH + 16 * w + c) * NN + 8 * g;
  const unsigned short* srcV2 = srcV1 + 32;                    // kh=1
  unsigned short* kdst = &sm.tl.Kf[0][w][lane][0];
  unsigned short* vdst = &sm.tl.Vf[0][w][lane][0];

#define STAGE(buf, mt_) do {                                   \
    const size_t mo_ = (size_t)(mt_) * 64;                     \
    gload16(srcK1 + mo_ * DH, kdst + (buf) * 4096);            \
    gload16(srcK2 + mo_ * DH, kdst + (buf) * 4096 + 2048);     \
    gload16(srcV1 + mo_, vdst + (buf) * 4096);                 \
    gload16(srcV2 + mo_, vdst + (buf) * 4096 + 2048);          \
  } while (0)

#define TILEBODY(m0_, cur_, MASKED_) do {                                      \
    const int m0 = (m0_);                                                      \
    const f32x4 f0a = *(const f32x4*)(fbase + m0);                             \
    const f32x4 f0b = *(const f32x4*)(fbase + m0 + 4);                         \
    const f32x4 f1a = *(const f32x4*)(fbase + m0 + 32);                        \
    const f32x4 f1b = *(const f32x4*)(fbase + m0 + 36);                        \
    const unsigned short* kbL = &sm.tl.Kf[cur_][0][lane][0];                   \
    f32x4 z = {0.f, 0.f, 0.f, 0.f};                                            \
    __builtin_amdgcn_s_setprio(1);                                             \
    f32x4 st00 = __builtin_amdgcn_mfma_f32_16x16x32_bf16(*(const short8*)(kbL + 0 * 512), qf0, z, 0, 0, 0); \
    st00 = __builtin_amdgcn_mfma_f32_16x16x32_bf16(*(const short8*)(kbL + 1 * 512), qf1, st00, 0, 0, 0);    \
    f32x4 st01 = __builtin_amdgcn_mfma_f32_16x16x32_bf16(*(const short8*)(kbL + 2 * 512), qf0, z, 0, 0, 0); \
    st01 = __builtin_amdgcn_mfma_f32_16x16x32_bf16(*(const short8*)(kbL + 3 * 512), qf1, st01, 0, 0, 0);    \
    f32x4 st10 = __builtin_amdgcn_mfma_f32_16x16x32_bf16(*(const short8*)(kbL + 4 * 512), qf0, z, 0, 0, 0); \
    st10 = __builtin_amdgcn_mfma_f32_16x16x32_bf16(*(const short8*)(kbL + 5 * 512), qf1, st10, 0, 0, 0);    \
    f32x4 st11 = __builtin_amdgcn_mfma_f32_16x16x32_bf16(*(const short8*)(kbL + 6 * 512), qf0, z, 0, 0, 0); \
    st11 = __builtin_amdgcn_mfma_f32_16x16x32_bf16(*(const short8*)(kbL + 7 * 512), qf1, st11, 0, 0, 0);    \
    __builtin_amdgcn_s_setprio(0);                                             \
    float pp[16];                                                              \
    float tmax = -INFINITY;                                                    \
    _Pragma("unroll")                                                          \
    for (int j = 0; j < 8; ++j) {                                              \
      float x0 = fmaf((j < 4) ? st00[j] : st01[j - 4], 0.125f, -((j < 4) ? f0a[j] : f0b[j - 4])); \
      float x1 = fmaf((j < 4) ? st10[j] : st11[j - 4], 0.125f, -((j < 4) ? f1a[j] : f1b[j - 4])); \
      if (MASKED_) {                                                           \
        const int mr0 = 8 * g + j;                                             \
        if (m0 + mr0 > qabs) x0 = -INFINITY;                                   \
        if (m0 + 32 + mr0 > qabs) x1 = -INFINITY;                              \
      }                                                                        \
      pp[j] = x0; pp[8 + j] = x1;                                              \
      tmax = fmaxf(tmax, fmaxf(x0, x1));                                       \
    }                                                                          \
    tmax = fmaxf(tmax, __shfl_xor(tmax, 16, 64));                              \
    tmax = fmaxf(tmax, __shfl_xor(tmax, 32, 64));                              \
    if (__all(tmax <= mrun)) {                                                 \
      float ts = 0.f;                                                          \
      _Pragma("unroll")                                                        \
      for (int j = 0; j < 16; ++j) { pp[j] = __expf(pp[j] - mrun); ts += pp[j]; } \
      ts += __shfl_xor(ts, 16, 64);                                            \
      ts += __shfl_xor(ts, 32, 64);                                            \
      lrun += ts;                                                              \
    } else {                                                                   \
      const float nm = fmaxf(mrun, tmax);                                      \
      const float sc = __expf(mrun - nm);                                      \
      float ts = 0.f;                                                          \
      _Pragma("unroll")                                                        \
      for (int j = 0; j < 16; ++j) { pp[j] = __expf(pp[j] - nm); ts += pp[j]; } \
      ts += __shfl_xor(ts, 16, 64);                                            \
      ts += __shfl_xor(ts, 32, 64);                                            \
      lrun = lrun * sc + ts;                                                   \
      mrun = nm;                                                               \
      _Pragma("unroll")                                                        \
      for (int e = 0; e < 4; ++e) { o0[e] *= sc; o1[e] *= sc; o2[e] *= sc; o3[e] *= sc; } \
    }                                                                          \
    union { unsigned u[4]; short8 v; } pf0, pf1;                               \
    _Pragma("unroll")                                                          \
    for (int q2 = 0; q2 < 4; ++q2) {                                           \
      pf0.u[q2] = (unsigned)f2bf(pp[2 * q2]) | ((unsigned)f2bf(pp[2 * q2 + 1]) << 16);          \
      pf1.u[q2] = (unsigned)f2bf(pp[8 + 2 * q2]) | ((unsigned)f2bf(pp[8 + 2 * q2 + 1]) << 16);  \
    }                                                                          \
    const unsigned short* vbL = &sm.tl.Vf[cur_][0][lane][0];                   \
    __builtin_amdgcn_s_setprio(1);                                             \
    o0 = __builtin_amdgcn_mfma_f32_16x16x32_bf16(*(const short8*)(vbL + 0 * 512), pf0.v, o0, 0, 0, 0); \
    o1 = __builtin_amdgcn_mfma_f32_16x16x32_bf16(*(const short8*)(vbL + 1 * 512), pf0.v, o1, 0, 0, 0); \
    o2 = __builtin_amdgcn_mfma_f32_16x16x32_bf16(*(const short8*)(vbL + 2 * 512), pf0.v, o2, 0, 0, 0); \
    o3 = __builtin_amdgcn_mfma_f32_16x16x32_bf16(*(const short8*)(vbL + 3 * 512), pf0.v, o3, 0, 0, 0); \
    o0 = __builtin_amdgcn_mfma_f32_16x16x32_bf16(*(const short8*)(vbL + 4 * 512), pf1.v, o0, 0, 0, 0); \
    o1 = __builtin_amdgcn_mfma_f32_16x16x32_bf16(*(const short8*)(vbL + 5 * 512), pf1.v, o1, 0, 0, 0); \
    o2 = __builtin_amdgcn_mfma_f32_16x16x32_bf16(*(const short8*)(vbL + 6 * 512), pf1.v, o2, 0, 0, 0); \
    o3 = __builtin_amdgcn_mfma_f32_16x16x32_bf16(*(const short8*)(vbL + 7 * 512), pf1.v, o3, 0, 0, 0); \
    __builtin_amdgcn_s_setprio(0);                                             \
  } while (0)

  #pragma unroll 1
  for (int p = 0; p < 2; ++p) {
    const int qb = p ? (31 - bx) : bx;
    const int q0w = qb * 64 + w * 16;
    const int qabs = q0w + c;
    const short8* qp = (const short8*)(Qh + (bh * NN + qabs) * DH + g * 8);
    const short8 qf0 = qp[0];
    const short8 qf1 = qp[4];
    const float* fbase = F + ((size_t)b * NN + qabs) * NN + 8 * g;
    f32x4 o0 = {0.f, 0.f, 0.f, 0.f}, o1 = o0, o2 = o0, o3 = o0;
    float mrun = -INFINITY, lrun = 0.f;
    const int nt = qb + 1;

    __builtin_amdgcn_s_barrier();          // protect LDS reuse across pair halves
    STAGE(0, 0);
    asm volatile("s_waitcnt vmcnt(0)" ::: "memory");
    __builtin_amdgcn_s_barrier();

    #pragma unroll 1
    for (int mt = 0; mt < nt - 1; ++mt) {  // mask-free main loop
      const int cur = mt & 1;
      STAGE(cur ^ 1, mt + 1);
      TILEBODY(mt * 64, cur, 0);
      asm volatile("s_waitcnt vmcnt(0)" ::: "memory");
      __builtin_amdgcn_s_barrier();
    }
    TILEBODY((nt - 1) * 64, (nt - 1) & 1, 1);  // masked tail tile

    // epilogue: transpose via LDS, write Oh (b,n,f) bf16 coalesced
    __syncthreads();                        // all tail-tile LDS reads done
    const float invl = 1.f / lrun;
    #pragma unroll
    for (int r = 0; r < 4; ++r) {
      sm.Ot[w][c][0 * 16 + 4 * g + r] = o0[r] * invl;
      sm.Ot[w][c][1 * 16 + 4 * g + r] = o1[r] * invl;
      sm.Ot[w][c][2 * 16 + 4 * g + r] = o2[r] * invl;
      sm.Ot[w][c][3 * 16 + 4 * g + r] = o3[r] * invl;
    }
    __syncthreads();
    {
      const int q2 = lane >> 2, d0 = (lane & 3) * 16;
      unsigned short tmp[16];
      #pragma unroll
      for (int i = 0; i < 16; ++i) tmp[i] = f2bf(sm.Ot[w][q2][d0 + i]);
      unsigned short* dst = Oh + ((size_t)b * NN + q0w + q2) * DM + h * DH + d0;
      *(short8*)dst = *(const short8*)&tmp[0];
      *(short8*)(dst + 8) = *(const short8*)&tmp[8];
    }
    __syncthreads();
  }
#undef TILEBODY
#undef STAGE
}

// ---------------------------------------------------------------------------
extern "C" void kernel_launch(void* const* d_in, const int* in_sizes, int n_in,
                              void* d_out, int out_size, void* d_ws, size_t ws_size,
                              hipStream_t stream) {
  (void)in_sizes; (void)n_in; (void)out_size; (void)ws_size;
  const float* X  = (const float*)d_in[0];
  const float* Wq = (const float*)d_in[1];
  const float* Wk = (const float*)d_in[2];
  const float* Wv = (const float*)d_in[3];
  const float* Wo = (const float*)d_in[4];
  const float* gq = (const float*)d_in[5];
  const float* bq = (const float*)d_in[6];
  const float* gk = (const float*)d_in[7];
  const float* bk = (const float*)d_in[8];

  float* out = (float*)d_out;                        // (B,N,D) f32
  float* Fm  = out + (size_t)BB * NN * DM;           // (B,N,N) f32

  const size_t E = (size_t)BB * NN * DM;             // 8388608
  // ws layout (~127 MB):
  //  fbuf: 8192x2048 f32 (67MB) — phase A: fused QK gemm out; phase B: V f32
  //        in bytes [0,33.5MB) + Vt bf16 at bytes [33.5MB,50.3MB)
  float* fbuf = (float*)d_ws;
  unsigned short* Vt = (unsigned short*)(fbuf + E);  // inside fbuf region
  unsigned short* Xh = (unsigned short*)(fbuf + 2 * E);  // also reused as Oh
  unsigned short* Qh = Xh + E;
  unsigned short* Kh = Qh + E;
  unsigned short* Wh = Kh + E;                       // 4 x 1M bf16 weights
  float* BS = (float*)(Wh + 4 * 1048576);            // (B,32,NN) f32 tile sums
  unsigned short* Oh = Xh;

  const int M = BB * NN;                             // 8192

  pack_bf16<<<4096, 256, 0, stream>>>(X, Xh, 1048576);
  pack_bf16<<<512, 256, 0, stream>>>(Wq, Wh + 0 * 1048576, 131072);
  pack_bf16<<<512, 256, 0, stream>>>(Wk, Wh + 1 * 1048576, 131072);
  pack_bf16<<<512, 256, 0, stream>>>(Wv, Wh + 2 * 1048576, 131072);
  pack_bf16<<<512, 256, 0, stream>>>(Wo, Wh + 3 * 1048576, 131072);

  // fused Q|K projection: C[8192][2048] f32
  gemm_bf16<<<dim3(16, 64), 256, 0, stream>>>(Xh, Wh, fbuf, M, 2048, DM);
  ln_pack<<<M, 256, 0, stream>>>(fbuf, 2048, gq, bq, Qh);
  ln_pack<<<M, 256, 0, stream>>>(fbuf + 1024, 2048, gk, bk, Kh);

  // V projection into fbuf bytes [0,33.5MB), then transpose-pack to Vt
  gemm_bf16<<<dim3(8, 64), 256, 0, stream>>>(Xh, Wh + 2 * 1048576, fbuf, M, DM, DM);
  vpack<<<4096, 256, 0, stream>>>(fbuf, Vt);

  fmask_part1<<<dim3(8, 32, 4), 256, 0, stream>>>(Qh, Kh, Fm, BS);
  fmask_part2<<<dim3(8, 31, 4), 256, 0, stream>>>(BS, Fm);

  attn_mfma<<<dim3(1024), 256, 0, stream>>>(Qh, Kh, Vt, Fm, Oh);
  gemm_bf16<<<dim3(8, 64), 256, 0, stream>>>(Oh, Wh + 3 * 1048576, out, M, DM, DM);
}

// Round 7
// 516.802 us; speedup vs baseline: 1.0250x; 1.0250x over previous
//
#include <hip/hip_runtime.h>
#include <hip/hip_bf16.h>
#include <math.h>

// Problem constants
#define BB 4
#define NN 2048
#define DM 1024
#define NH 16
#define DH 64

typedef short short8 __attribute__((ext_vector_type(8)));
typedef float f32x4 __attribute__((ext_vector_type(4)));

static __device__ __forceinline__ unsigned short f2bf(float x) {
  unsigned u = __builtin_bit_cast(unsigned, x);
  u += 0x7fffu + ((u >> 16) & 1u);            // RNE
  return (unsigned short)(u >> 16);
}
static __device__ __forceinline__ float bf2f(short s) {
  return __builtin_bit_cast(float, ((unsigned)(unsigned short)s) << 16);
}

typedef __attribute__((address_space(1))) const void gv_t;
typedef __attribute__((address_space(3))) void lv_t;
static __device__ __forceinline__ void gload16(const void* gsrc, void* ldst) {
  __builtin_amdgcn_global_load_lds((gv_t*)gsrc, (lv_t*)ldst, 16, 0, 0);
}

// ---------------------------------------------------------------------------
// pack f32 -> bf16, 8 elems/thread
// ---------------------------------------------------------------------------
__global__ __launch_bounds__(256) void pack_bf16(const float* __restrict__ in,
                                                 unsigned short* __restrict__ out,
                                                 int n8) {
  const int i = blockIdx.x * 256 + threadIdx.x;
  if (i >= n8) return;
  const float4* p = (const float4*)in + 2 * (size_t)i;
  const float4 x = p[0], y = p[1];
  unsigned short tmp[8] = {f2bf(x.x), f2bf(x.y), f2bf(x.z), f2bf(x.w),
                           f2bf(y.x), f2bf(y.y), f2bf(y.z), f2bf(y.w)};
  *(short8*)(out + 8 * (size_t)i) = *(const short8*)tmp;
}

// ---------------------------------------------------------------------------
// bf16 MFMA GEMM: C[M,N] f32 = A[M,K] * B[N,K]^T (both bf16 row-major).
// 128x128 tile, BK=32, 4 waves (2x2), 4x4 frags of 16x16x32 per wave.
// ---------------------------------------------------------------------------
__global__ __launch_bounds__(256) void gemm_bf16(const unsigned short* __restrict__ A,
                                                 const unsigned short* __restrict__ Bw,
                                                 float* __restrict__ C,
                                                 int M, int N, int K) {
  __shared__ unsigned short As[128 * 32];
  __shared__ unsigned short Bs[128 * 32];
  const int t = threadIdx.x;
  const int row0 = blockIdx.y * 128, col0 = blockIdx.x * 128;
  const int lane = t & 63, w = t >> 6;
  const int wr = (w >> 1) * 64, wc = (w & 1) * 64;
  const int g = lane >> 4, c = lane & 15;

  f32x4 acc[4][4];
  #pragma unroll
  for (int i = 0; i < 4; ++i)
    #pragma unroll
    for (int j = 0; j < 4; ++j) acc[i][j] = (f32x4){0.f, 0.f, 0.f, 0.f};

  const unsigned short* Asrc = A + (size_t)(row0 + (t >> 2)) * K + (t & 3) * 8;
  const unsigned short* Bsrc = Bw + (size_t)(col0 + (t >> 2)) * K + (t & 3) * 8;
  unsigned short* dA0 = &As[t * 8];
  unsigned short* dA1 = &As[2048 + t * 8];
  unsigned short* dB0 = &Bs[t * 8];
  unsigned short* dB1 = &Bs[2048 + t * 8];

  for (int kt = 0; kt < K; kt += 32) {
    __syncthreads();
    gload16(Asrc + kt, dA0);
    gload16(Asrc + (size_t)64 * K + kt, dA1);
    gload16(Bsrc + kt, dB0);
    gload16(Bsrc + (size_t)64 * K + kt, dB1);
    __syncthreads();
    short8 a[4], bf[4];
    #pragma unroll
    for (int i = 0; i < 4; ++i)
      a[i] = *(const short8*)&As[(wr + i * 16 + c) * 32 + g * 8];
    #pragma unroll
    for (int j = 0; j < 4; ++j)
      bf[j] = *(const short8*)&Bs[(wc + j * 16 + c) * 32 + g * 8];
    #pragma unroll
    for (int i = 0; i < 4; ++i)
      #pragma unroll
      for (int j = 0; j < 4; ++j)
        acc[i][j] = __builtin_amdgcn_mfma_f32_16x16x32_bf16(a[i], bf[j], acc[i][j], 0, 0, 0);
  }
  #pragma unroll
  for (int i = 0; i < 4; ++i) {
    #pragma unroll
    for (int r = 0; r < 4; ++r) {
      float* cp = C + (size_t)(row0 + wr + i * 16 + 4 * g + r) * N + col0 + wc + c;
      #pragma unroll
      for (int j = 0; j < 4; ++j) cp[j * 16] = acc[i][j][r];
    }
  }
}

// ---------------------------------------------------------------------------
// LayerNorm + bf16 pack: row of 1024 f32 (stride ldy) -> (b,h,n,d) bf16
// ---------------------------------------------------------------------------
__global__ __launch_bounds__(256) void ln_pack(const float* __restrict__ Y, int ldy,
                                               const float* __restrict__ g,
                                               const float* __restrict__ bb,
                                               unsigned short* __restrict__ out) {
  const int t = threadIdx.x;
  const int bidx = blockIdx.x >> 11;
  const int n = blockIdx.x & 2047;
  const float* y = Y + (size_t)blockIdx.x * ldy;
  float4 v = ((const float4*)y)[t];
  __shared__ float red[4];
  float s = v.x + v.y + v.z + v.w;
  #pragma unroll
  for (int off = 1; off < 64; off <<= 1) s += __shfl_xor(s, off, 64);
  if ((t & 63) == 0) red[t >> 6] = s;
  __syncthreads();
  const float mean = (red[0] + red[1] + red[2] + red[3]) * (1.f / 1024.f);
  const float dx = v.x - mean, dy = v.y - mean, dz = v.z - mean, dw = v.w - mean;
  float sq = dx * dx + dy * dy + dz * dz + dw * dw;
  #pragma unroll
  for (int off = 1; off < 64; off <<= 1) sq += __shfl_xor(sq, off, 64);
  __syncthreads();
  if ((t & 63) == 0) red[t >> 6] = sq;
  __syncthreads();
  const float inv = rsqrtf((red[0] + red[1] + red[2] + red[3]) * (1.f / 1024.f) + 1e-5f);
  const float4 gv = ((const float4*)g)[t];
  const float4 bv = ((const float4*)bb)[t];
  ushort4 w4;
  w4.x = f2bf(dx * inv * gv.x + bv.x);
  w4.y = f2bf(dy * inv * gv.y + bv.y);
  w4.z = f2bf(dz * inv * gv.z + bv.z);
  w4.w = f2bf(dw * inv * gv.w + bv.w);
  unsigned short* dst = out + (((size_t)bidx * NH + (t >> 4)) * NN + n) * DH + (t & 15) * 4;
  *(ushort4*)dst = w4;
}

// ---------------------------------------------------------------------------
// V pack + transpose: (b,n,f) f32 -> Vt (b,h,d,m) bf16
// ---------------------------------------------------------------------------
__global__ __launch_bounds__(256) void vpack(const float* __restrict__ V,
                                             unsigned short* __restrict__ Vt) {
  const int tid = blockIdx.x * 256 + threadIdx.x;
  const int d = tid & 63;
  const int rest = tid >> 6;
  const int m0 = (rest & 255) * 8;
  const int h = (rest >> 8) & 15;
  const int b = rest >> 12;
  const float* src = V + ((size_t)b * NN + m0) * DM + h * DH + d;
  unsigned short tmp[8];
  #pragma unroll
  for (int i = 0; i < 8; ++i) tmp[i] = f2bf(src[(size_t)i * DM]);
  unsigned short* dst = Vt + (((size_t)b * NH + h) * DH + d) * NN + m0;
  *(short8*)dst = *(const short8*)tmp;
}

// ---------------------------------------------------------------------------
// F_mask part1: per 64-row tile local prefix + tile sums.
// 1 column/thread (grid 8x32x4) + 4-way partial accumulators.
// ---------------------------------------------------------------------------
__global__ __launch_bounds__(256) void fmask_part1(const unsigned short* __restrict__ Qh,
                                                   const unsigned short* __restrict__ Kh,
                                                   float* __restrict__ Fm,
                                                   float* __restrict__ BS) {
  const int b = blockIdx.z, tl = blockIdx.y;
  const int m = blockIdx.x * 256 + threadIdx.x;
  const int n0 = tl * 64;
  float kr[64];
  {
    const short8* kp = (const short8*)(Kh + ((size_t)b * NH * NN + m) * DH);
    #pragma unroll
    for (int i = 0; i < 8; ++i) {
      short8 kv = kp[i];
      #pragma unroll
      for (int j = 0; j < 8; ++j) kr[i * 8 + j] = bf2f(kv[j]);
    }
  }
  const float4* kv4 = (const float4*)kr;
  __shared__ float Qs[64][68];
  {
    const int row = threadIdx.x >> 2;
    const int c0 = (threadIdx.x & 3) * 16;
    const short8* qp = (const short8*)(Qh + ((size_t)b * NH * NN + n0 + row) * DH + c0);
    short8 qa = qp[0], qb2 = qp[1];
    #pragma unroll
    for (int j = 0; j < 8; ++j) {
      Qs[row][c0 + j] = bf2f(qa[j]);
      Qs[row][c0 + 8 + j] = bf2f(qb2[j]);
    }
  }
  __syncthreads();
  float run = 0.f;
  float* Fp = Fm + (size_t)b * NN * NN + m;
  for (int nn = 0; nn < 64; ++nn) {
    const int n = n0 + nn;
    Fp[(size_t)n * NN] = run;
    float d[4] = {0.f, 0.f, 0.f, 0.f};
    #pragma unroll
    for (int i = 0; i < 16; ++i) {
      const float4 qv = *(const float4*)&Qs[nn][i * 4];
      const float4 kv = kv4[i];
      d[i & 3] = fmaf(qv.x, kv.x, d[i & 3]);
      d[i & 3] = fmaf(qv.y, kv.y, d[i & 3]);
      d[i & 3] = fmaf(qv.z, kv.z, d[i & 3]);
      d[i & 3] = fmaf(qv.w, kv.w, d[i & 3]);
    }
    const float dot = (d[0] + d[1]) + (d[2] + d[3]);
    if (m >= 1 && m < n) run += fmaxf(dot * 0.125f, 0.f);
  }
  BS[((size_t)b * 32 + tl) * NN + m] = run;
}

// ---------------------------------------------------------------------------
// F_mask part2: add cross-tile prefix. grid (mc=8, t-1=31, b=4).
// ---------------------------------------------------------------------------
__global__ __launch_bounds__(256) void fmask_part2(const float* __restrict__ BS,
                                                   float* __restrict__ Fm) {
  const int b = blockIdx.z;
  const int tlt = blockIdx.y + 1;  // 1..31
  const int m = blockIdx.x * 256 + threadIdx.x;
  float pre = 0.f;
  const float* bs = BS + (size_t)b * 32 * NN + m;
  for (int t2 = 0; t2 < tlt; ++t2) pre += bs[(size_t)t2 * NN];
  float* Fp = Fm + ((size_t)b * NN + tlt * 64) * NN + m;
  #pragma unroll 4
  for (int nn = 0; nn < 64; ++nn) Fp[(size_t)nn * NN] += pre;
}

// ---------------------------------------------------------------------------
// MFMA flash attention v4: 4 waves / 64 q-rows, 64-m tiles, double-buffered
// 2-phase pipeline, causal pair balancing {bx, 31-bx}, XCD swizzle.
// Round-7 change: REVERT defer-max (round-6 regression: the __all branch
// between QK-MFMA and PV-MFMA split the scheduling region — VALUBusy 46->32,
// VGPR 60->72, attn 154->171us). Straight-line always-rescale softmax
// (HW-verified rounds 2-5). Keep: XCD swizzle (FETCH 272->94MB confirmed),
// mask-free main loop + peeled masked tail.
// ---------------------------------------------------------------------------
__global__ __launch_bounds__(256) void attn_mfma(const unsigned short* __restrict__ Qh,
                                                 const unsigned short* __restrict__ Kh,
                                                 const unsigned short* __restrict__ Vt,
                                                 const float* __restrict__ F,
                                                 unsigned short* __restrict__ Oh) {
  const int t = threadIdx.x, lane = t & 63, w = t >> 6;
  const int g = lane >> 4, c = lane & 15;
  // XCD swizzle: 1024 blocks = 8 XCDs x 128; h fastest so one XCD's chunk
  // covers all 16 heads for the same (b, bx-range) -> F/K/V L2 reuse.
  const int id = blockIdx.x;
  const int idp = (id & 7) * 128 + (id >> 3);
  const int h  = idp & 15;
  const int bx = (idp >> 4) & 15;
  const int b  = idp >> 8;
  const size_t bh = (size_t)b * NH + h;

  __shared__ union {
    struct { unsigned short Kf[2][8][64][8]; unsigned short Vf[2][8][64][8]; } tl;
    float Ot[4][16][68];
  } sm;

  const int perm = 8 * (c >> 2) + (c & 3);
  const int kr1 = 32 * (w >> 2) + perm + 4 * ((w >> 1) & 1);   // w<4 -> s=0
  const unsigned short* srcK1 = Kh + (bh * NN + kr1) * DH + g * 8 + 32 * (w & 1);
  const unsigned short* srcK2 = srcK1 + (size_t)32 * DH;       // frag w+4 (s=1)
  const unsigned short* srcV1 = Vt + (bh * DH + 16 * w + c) * NN + 8 * g;
  const unsigned short* srcV2 = srcV1 + 32;                    // kh=1
  unsigned short* kdst = &sm.tl.Kf[0][w][lane][0];
  unsigned short* vdst = &sm.tl.Vf[0][w][lane][0];

#define STAGE(buf, mt_) do {                                   \
    const size_t mo_ = (size_t)(mt_) * 64;                     \
    gload16(srcK1 + mo_ * DH, kdst + (buf) * 4096);            \
    gload16(srcK2 + mo_ * DH, kdst + (buf) * 4096 + 2048);     \
    gload16(srcV1 + mo_, vdst + (buf) * 4096);                 \
    gload16(srcV2 + mo_, vdst + (buf) * 4096 + 2048);          \
  } while (0)

#define TILEBODY(m0_, cur_, MASKED_) do {                                      \
    const int m0 = (m0_);                                                      \
    const f32x4 f0a = *(const f32x4*)(fbase + m0);                             \
    const f32x4 f0b = *(const f32x4*)(fbase + m0 + 4);                         \
    const f32x4 f1a = *(const f32x4*)(fbase + m0 + 32);                        \
    const f32x4 f1b = *(const f32x4*)(fbase + m0 + 36);                        \
    const unsigned short* kbL = &sm.tl.Kf[cur_][0][lane][0];                   \
    f32x4 z = {0.f, 0.f, 0.f, 0.f};                                            \
    __builtin_amdgcn_s_setprio(1);                                             \
    f32x4 st00 = __builtin_amdgcn_mfma_f32_16x16x32_bf16(*(const short8*)(kbL + 0 * 512), qf0, z, 0, 0, 0); \
    st00 = __builtin_amdgcn_mfma_f32_16x16x32_bf16(*(const short8*)(kbL + 1 * 512), qf1, st00, 0, 0, 0);    \
    f32x4 st01 = __builtin_amdgcn_mfma_f32_16x16x32_bf16(*(const short8*)(kbL + 2 * 512), qf0, z, 0, 0, 0); \
    st01 = __builtin_amdgcn_mfma_f32_16x16x32_bf16(*(const short8*)(kbL + 3 * 512), qf1, st01, 0, 0, 0);    \
    f32x4 st10 = __builtin_amdgcn_mfma_f32_16x16x32_bf16(*(const short8*)(kbL + 4 * 512), qf0, z, 0, 0, 0); \
    st10 = __builtin_amdgcn_mfma_f32_16x16x32_bf16(*(const short8*)(kbL + 5 * 512), qf1, st10, 0, 0, 0);    \
    f32x4 st11 = __builtin_amdgcn_mfma_f32_16x16x32_bf16(*(const short8*)(kbL + 6 * 512), qf0, z, 0, 0, 0); \
    st11 = __builtin_amdgcn_mfma_f32_16x16x32_bf16(*(const short8*)(kbL + 7 * 512), qf1, st11, 0, 0, 0);    \
    __builtin_amdgcn_s_setprio(0);                                             \
    float pp[16];                                                              \
    float tmax = -INFINITY;                                                    \
    _Pragma("unroll")                                                          \
    for (int j = 0; j < 8; ++j) {                                              \
      float x0 = fmaf((j < 4) ? st00[j] : st01[j - 4], 0.125f, -((j < 4) ? f0a[j] : f0b[j - 4])); \
      float x1 = fmaf((j < 4) ? st10[j] : st11[j - 4], 0.125f, -((j < 4) ? f1a[j] : f1b[j - 4])); \
      if (MASKED_) {                                                           \
        const int mr0 = 8 * g + j;                                             \
        if (m0 + mr0 > qabs) x0 = -INFINITY;                                   \
        if (m0 + 32 + mr0 > qabs) x1 = -INFINITY;                              \
      }                                                                        \
      pp[j] = x0; pp[8 + j] = x1;                                              \
      tmax = fmaxf(tmax, fmaxf(x0, x1));                                       \
    }                                                                          \
    tmax = fmaxf(tmax, __shfl_xor(tmax, 16, 64));                              \
    tmax = fmaxf(tmax, __shfl_xor(tmax, 32, 64));                              \
    const float nm = fmaxf(mrun, tmax);                                        \
    const float sc = __expf(mrun - nm);                                        \
    float ts = 0.f;                                                            \
    _Pragma("unroll")                                                          \
    for (int j = 0; j < 16; ++j) { pp[j] = __expf(pp[j] - nm); ts += pp[j]; }  \
    ts += __shfl_xor(ts, 16, 64);                                              \
    ts += __shfl_xor(ts, 32, 64);                                              \
    lrun = lrun * sc + ts;                                                     \
    mrun = nm;                                                                 \
    _Pragma("unroll")                                                          \
    for (int e = 0; e < 4; ++e) { o0[e] *= sc; o1[e] *= sc; o2[e] *= sc; o3[e] *= sc; } \
    union { unsigned u[4]; short8 v; } pf0, pf1;                               \
    _Pragma("unroll")                                                          \
    for (int q2 = 0; q2 < 4; ++q2) {                                           \
      pf0.u[q2] = (unsigned)f2bf(pp[2 * q2]) | ((unsigned)f2bf(pp[2 * q2 + 1]) << 16);          \
      pf1.u[q2] = (unsigned)f2bf(pp[8 + 2 * q2]) | ((unsigned)f2bf(pp[8 + 2 * q2 + 1]) << 16);  \
    }                                                                          \
    const unsigned short* vbL = &sm.tl.Vf[cur_][0][lane][0];                   \
    __builtin_amdgcn_s_setprio(1);                                             \
    o0 = __builtin_amdgcn_mfma_f32_16x16x32_bf16(*(const short8*)(vbL + 0 * 512), pf0.v, o0, 0, 0, 0); \
    o1 = __builtin_amdgcn_mfma_f32_16x16x32_bf16(*(const short8*)(vbL + 1 * 512), pf0.v, o1, 0, 0, 0); \
    o2 = __builtin_amdgcn_mfma_f32_16x16x32_bf16(*(const short8*)(vbL + 2 * 512), pf0.v, o2, 0, 0, 0); \
    o3 = __builtin_amdgcn_mfma_f32_16x16x32_bf16(*(const short8*)(vbL + 3 * 512), pf0.v, o3, 0, 0, 0); \
    o0 = __builtin_amdgcn_mfma_f32_16x16x32_bf16(*(const short8*)(vbL + 4 * 512), pf1.v, o0, 0, 0, 0); \
    o1 = __builtin_amdgcn_mfma_f32_16x16x32_bf16(*(const short8*)(vbL + 5 * 512), pf1.v, o1, 0, 0, 0); \
    o2 = __builtin_amdgcn_mfma_f32_16x16x32_bf16(*(const short8*)(vbL + 6 * 512), pf1.v, o2, 0, 0, 0); \
    o3 = __builtin_amdgcn_mfma_f32_16x16x32_bf16(*(const short8*)(vbL + 7 * 512), pf1.v, o3, 0, 0, 0); \
    __builtin_amdgcn_s_setprio(0);                                             \
  } while (0)

  #pragma unroll 1
  for (int p = 0; p < 2; ++p) {
    const int qb = p ? (31 - bx) : bx;
    const int q0w = qb * 64 + w * 16;
    const int qabs = q0w + c;
    const short8* qp = (const short8*)(Qh + (bh * NN + qabs) * DH + g * 8);
    const short8 qf0 = qp[0];
    const short8 qf1 = qp[4];
    const float* fbase = F + ((size_t)b * NN + qabs) * NN + 8 * g;
    f32x4 o0 = {0.f, 0.f, 0.f, 0.f}, o1 = o0, o2 = o0, o3 = o0;
    float mrun = -INFINITY, lrun = 0.f;
    const int nt = qb + 1;

    __builtin_amdgcn_s_barrier();          // protect LDS reuse across pair halves
    STAGE(0, 0);
    asm volatile("s_waitcnt vmcnt(0)" ::: "memory");
    __builtin_amdgcn_s_barrier();

    #pragma unroll 1
    for (int mt = 0; mt < nt - 1; ++mt) {  // mask-free main loop
      const int cur = mt & 1;
      STAGE(cur ^ 1, mt + 1);
      TILEBODY(mt * 64, cur, 0);
      asm volatile("s_waitcnt vmcnt(0)" ::: "memory");
      __builtin_amdgcn_s_barrier();
    }
    TILEBODY((nt - 1) * 64, (nt - 1) & 1, 1);  // masked tail tile

    // epilogue: transpose via LDS, write Oh (b,n,f) bf16 coalesced
    __syncthreads();                        // all tail-tile LDS reads done
    const float invl = 1.f / lrun;
    #pragma unroll
    for (int r = 0; r < 4; ++r) {
      sm.Ot[w][c][0 * 16 + 4 * g + r] = o0[r] * invl;
      sm.Ot[w][c][1 * 16 + 4 * g + r] = o1[r] * invl;
      sm.Ot[w][c][2 * 16 + 4 * g + r] = o2[r] * invl;
      sm.Ot[w][c][3 * 16 + 4 * g + r] = o3[r] * invl;
    }
    __syncthreads();
    {
      const int q2 = lane >> 2, d0 = (lane & 3) * 16;
      unsigned short tmp[16];
      #pragma unroll
      for (int i = 0; i < 16; ++i) tmp[i] = f2bf(sm.Ot[w][q2][d0 + i]);
      unsigned short* dst = Oh + ((size_t)b * NN + q0w + q2) * DM + h * DH + d0;
      *(short8*)dst = *(const short8*)&tmp[0];
      *(short8*)(dst + 8) = *(const short8*)&tmp[8];
    }
    __syncthreads();
  }
#undef TILEBODY
#undef STAGE
}

// ---------------------------------------------------------------------------
extern "C" void kernel_launch(void* const* d_in, const int* in_sizes, int n_in,
                              void* d_out, int out_size, void* d_ws, size_t ws_size,
                              hipStream_t stream) {
  (void)in_sizes; (void)n_in; (void)out_size; (void)ws_size;
  const float* X  = (const float*)d_in[0];
  const float* Wq = (const float*)d_in[1];
  const float* Wk = (const float*)d_in[2];
  const float* Wv = (const float*)d_in[3];
  const float* Wo = (const float*)d_in[4];
  const float* gq = (const float*)d_in[5];
  const float* bq = (const float*)d_in[6];
  const float* gk = (const float*)d_in[7];
  const float* bk = (const float*)d_in[8];

  float* out = (float*)d_out;                        // (B,N,D) f32
  float* Fm  = out + (size_t)BB * NN * DM;           // (B,N,N) f32

  const size_t E = (size_t)BB * NN * DM;             // 8388608
  // ws layout (~127 MB):
  //  fbuf: 8192x2048 f32 (67MB) — phase A: fused QK gemm out; phase B: V f32
  //        in bytes [0,33.5MB) + Vt bf16 at bytes [33.5MB,50.3MB)
  float* fbuf = (float*)d_ws;
  unsigned short* Vt = (unsigned short*)(fbuf + E);  // inside fbuf region
  unsigned short* Xh = (unsigned short*)(fbuf + 2 * E);  // also reused as Oh
  unsigned short* Qh = Xh + E;
  unsigned short* Kh = Qh + E;
  unsigned short* Wh = Kh + E;                       // 4 x 1M bf16 weights
  float* BS = (float*)(Wh + 4 * 1048576);            // (B,32,NN) f32 tile sums
  unsigned short* Oh = Xh;

  const int M = BB * NN;                             // 8192

  pack_bf16<<<4096, 256, 0, stream>>>(X, Xh, 1048576);
  pack_bf16<<<512, 256, 0, stream>>>(Wq, Wh + 0 * 1048576, 131072);
  pack_bf16<<<512, 256, 0, stream>>>(Wk, Wh + 1 * 1048576, 131072);
  pack_bf16<<<512, 256, 0, stream>>>(Wv, Wh + 2 * 1048576, 131072);
  pack_bf16<<<512, 256, 0, stream>>>(Wo, Wh + 3 * 1048576, 131072);

  // fused Q|K projection: C[8192][2048] f32
  gemm_bf16<<<dim3(16, 64), 256, 0, stream>>>(Xh, Wh, fbuf, M, 2048, DM);
  ln_pack<<<M, 256, 0, stream>>>(fbuf, 2048, gq, bq, Qh);
  ln_pack<<<M, 256, 0, stream>>>(fbuf + 1024, 2048, gk, bk, Kh);

  // V projection into fbuf bytes [0,33.5MB), then transpose-pack to Vt
  gemm_bf16<<<dim3(8, 64), 256, 0, stream>>>(Xh, Wh + 2 * 1048576, fbuf, M, DM, DM);
  vpack<<<4096, 256, 0, stream>>>(fbuf, Vt);

  fmask_part1<<<dim3(8, 32, 4), 256, 0, stream>>>(Qh, Kh, Fm, BS);
  fmask_part2<<<dim3(8, 31, 4), 256, 0, stream>>>(BS, Fm);

  attn_mfma<<<dim3(1024), 256, 0, stream>>>(Qh, Kh, Vt, Fm, Oh);
  gemm_bf16<<<dim3(8, 64), 256, 0, stream>>>(Oh, Wh + 3 * 1048576, out, M, DM, DM);
}